// Round 2
// baseline (107.861 us; speedup 1.0000x reference)
//
#include <hip/hip_runtime.h>
#include <hip/hip_bf16.h>
#include <stdint.h>

typedef __bf16 bf16;
typedef __bf16 bf16x8 __attribute__((ext_vector_type(8)));
typedef __bf16 bf16x4 __attribute__((ext_vector_type(4)));
typedef float  f32x4  __attribute__((ext_vector_type(4)));

#define MFMA16(a, b, c) __builtin_amdgcn_mfma_f32_16x16x32_bf16((a), (b), (c), 0, 0, 0)

// Problem constants
#define BB   2
#define NN   4096
#define CC   256
#define HH   4
#define DD   64
#define BH   8          // BB*HH
#define SL2E 0.1803368801111244f   // (1/8) * log2(e), folded into Q

__device__ __forceinline__ void gload_lds16(const void* g, void* l) {
    __builtin_amdgcn_global_load_lds(
        (const __attribute__((address_space(1))) void*)g,
        (__attribute__((address_space(3))) void*)l, 16, 0, 0);
}

// ---------------------------------------------------------------------------
// fp32 -> bf16 convert, all three inputs in one launch.
// segment sizes (in float4): x 524288 | w_qkv 49152 | w_proj 16384
// ---------------------------------------------------------------------------
__global__ __launch_bounds__(256) void cvt_all(const float* __restrict__ x,
                                               const float* __restrict__ wq,
                                               const float* __restrict__ wp,
                                               bf16* __restrict__ xb,
                                               bf16* __restrict__ wqb,
                                               bf16* __restrict__ wpb) {
    int i = blockIdx.x * 256 + threadIdx.x;
    const float* src; bf16* dst; int j;
    if (i < 524288)      { src = x;  dst = xb;  j = i; }
    else if (i < 573440) { src = wq; dst = wqb; j = i - 524288; }
    else if (i < 589824) { src = wp; dst = wpb; j = i - 573440; }
    else return;
    f32x4 v = ((const f32x4*)src)[j];
    bf16x4 o;
    o[0] = (bf16)v[0]; o[1] = (bf16)v[1]; o[2] = (bf16)v[2]; o[3] = (bf16)v[3];
    ((bf16x4*)dst)[j] = o;
}

// ---------------------------------------------------------------------------
// QKV GEMM: X[8192][256] @ W[768][256]^T.
// Q written scaled by SL2E (so attention exp input is exp2-domain directly).
// V written transposed AND column-permuted as Vt [BH][D][N']:
// logical column kv = 32g+16u+4w+r stored at n' = 32g+8w+4u+r, so the
// flash PV A-fragment (psi-permuted k) is a contiguous 16B read.
// BM=128 (4 waves x 32 rows), BN=64. grid (64,12)
// ---------------------------------------------------------------------------
__global__ __launch_bounds__(256) void gemm_qkv(const bf16* __restrict__ X,
                                                const bf16* __restrict__ W,
                                                bf16* __restrict__ Q,
                                                bf16* __restrict__ K,
                                                bf16* __restrict__ Vt) {
    const int wave = threadIdx.x >> 6;
    const int lane = threadIdx.x & 63;
    const int lr = lane & 15;
    const int lg = lane >> 4;
    const int row0 = blockIdx.x * 128 + wave * 32;
    const int col0 = blockIdx.y * 64;

    f32x4 acc[2][4] = {};
    for (int k0 = 0; k0 < 256; k0 += 32) {
        bf16x8 a[2], b[4];
#pragma unroll
        for (int i = 0; i < 2; i++)
            a[i] = *(const bf16x8*)&X[(size_t)(row0 + 16 * i + lr) * 256 + k0 + 8 * lg];
#pragma unroll
        for (int t = 0; t < 4; t++)
            b[t] = *(const bf16x8*)&W[(size_t)(col0 + 16 * t + lr) * 256 + k0 + 8 * lg];
#pragma unroll
        for (int i = 0; i < 2; i++)
#pragma unroll
            for (int t = 0; t < 4; t++)
                acc[i][t] = MFMA16(a[i], b[t], acc[i][t]);
    }

    const int s = col0 >> 8;          // 0=Q 1=K 2=V
    const int h = (col0 >> 6) & 3;
    if (s == 2) {
#pragma unroll
        for (int i = 0; i < 2; i++) {
#pragma unroll
            for (int t = 0; t < 4; t++) {
                int row = row0 + 16 * i + 4 * lg;     // n base (4 consecutive)
                int d   = 16 * t + lr;
                int bh  = ((row >> 12) << 2) | h;
                int nb  = row & 4095;
                int g   = nb >> 5, m = (nb >> 2) & 7;
                int np  = (g << 5) + ((m & 3) << 3) + ((m >> 2) << 2);
                bf16x4 o4;
#pragma unroll
                for (int r = 0; r < 4; r++) o4[r] = (bf16)acc[i][t][r];
                *(bf16x4*)&Vt[((size_t)bh * DD + d) * NN + np] = o4;
            }
        }
    } else {
        bf16* dst = (s == 0) ? Q : K;
        const float sc = (s == 0) ? SL2E : 1.0f;
#pragma unroll
        for (int i = 0; i < 2; i++) {
#pragma unroll
            for (int t = 0; t < 4; t++) {
#pragma unroll
                for (int r = 0; r < 4; r++) {
                    int row = row0 + 16 * i + 4 * lg + r;
                    int d   = 16 * t + lr;
                    int bh  = ((row >> 12) << 2) | h;
                    int n   = row & 4095;
                    dst[((size_t)bh * NN + n) * DD + d] = (bf16)(acc[i][t][r] * sc);
                }
            }
        }
    }
}

// ---------------------------------------------------------------------------
// Flash attention: swapped 16x16 QK^T, TWO q-subtiles per wave (K/V LDS
// fragments shared -> LDS read traffic halved), in-register no-shift
// softmax, permuted-k PV with b128 V-fragments, psum via ones-MFMA,
// 2-buffer staging (counted vmcnt), kv-split across NSPLIT (template).
// 8 waves/block (512 thr, 256 q-rows) so 2 resident blocks/CU = 16 waves/CU;
// __launch_bounds__(512,4) caps regs at 128/wave so 4 waves/SIMD fit.
// XCD-aware bijective block swizzle for KV L2 locality.
// Partials: Op [z][8192][256] bf16 (AO layout, unnormalized), ps [z][BH][N] f32.
// grid (N/256, BH, NSPLIT), 512 threads (8 waves x 32 q-rows).
// ---------------------------------------------------------------------------
template<int NSPLIT>
__global__ __launch_bounds__(512, 4) void flash_attn(const bf16* __restrict__ Q,
                                                     const bf16* __restrict__ K,
                                                     const bf16* __restrict__ Vt,
                                                     bf16* __restrict__ Op,
                                                     float* __restrict__ ps) {
    __shared__ __align__(16) char kv_lds[2][16384];

    // bijective XCD swizzle: total = 128*NSPLIT blocks, chunk = total/8
    const int id  = blockIdx.x + 16 * (blockIdx.y + 8 * blockIdx.z);
    constexpr int CHUNK = 16 * NSPLIT;
    const int nid = (id & 7) * CHUNK + (id >> 3);
    const int qx  = nid & 15;            // q-block index
    const int g   = nid >> 4;
    const int bh  = g & 7;               // head index
    const int zid = g >> 3;              // kv-split index

    const int wave = threadIdx.x >> 6;
    const int lane = threadIdx.x & 63;
    const int lr   = lane & 15;
    const int lg   = lane >> 4;
    const int tid  = threadIdx.x;
    const int swz  = (lr & 7) << 4;

    const char* Khb  = (const char*)(K  + (size_t)bh * NN * DD);   // row stride 128B
    const char* Vthb = (const char*)(Vt + (size_t)bh * DD * NN);   // row stride 8192B
    const bf16* Qh   = Q + (size_t)bh * NN * DD;

    const int qw = qx * 256 + wave * 32;

    // Q B-fragments (pre-scaled by SL2E), 2 subtiles: q = qw + 16s + lr
    bf16x8 qf[2][2];
#pragma unroll
    for (int s = 0; s < 2; s++) {
        qf[s][0] = *(const bf16x8*)&Qh[(size_t)(qw + 16 * s + lr) * DD + 8 * lg];
        qf[s][1] = *(const bf16x8*)&Qh[(size_t)(qw + 16 * s + lr) * DD + 32 + 8 * lg];
    }

    const int L  = tid * 16;                       // 0..8176
    const int r0 = L >> 7;                         // 0..63
    const int c0 = (L & 127) ^ ((r0 & 7) << 4);    // inverse-swizzled source col

    bf16x8 onesf;
#pragma unroll
    for (int j = 0; j < 8; j++) onesf[j] = (bf16)1.0f;

    f32x4 oa[2][4] = {};     // [subtile][dt]: O[q][d=16dt+4lg+r] unnormalized
    f32x4 psacc[2] = {};     // per-subtile ones-MFMA psum

    auto stage = [&](int t, char* buf) {
        const int kv0 = t * 64;
        gload_lds16(Khb + (size_t)(kv0 + r0) * 128 + c0,     buf + L);
        gload_lds16(Vthb + (size_t)r0 * 8192 + kv0 * 2 + c0, buf + 8192 + L);
    };

    auto compute = [&](const char* buf) {
        const char* kb = buf;
        const char* vb = buf + 8192;

        // S^T = K . Q^T for both q-subtiles; K fragments read ONCE.
        f32x4 sacc[2][4];
        __builtin_amdgcn_s_setprio(1);
#pragma unroll
        for (int t = 0; t < 4; t++) {
            const char* rowk = kb + (16 * t + lr) * 128;
            bf16x8 kf0 = *(const bf16x8*)(rowk + ((16 * lg) ^ swz));
            bf16x8 kf1 = *(const bf16x8*)(rowk + ((64 + 16 * lg) ^ swz));
#pragma unroll
            for (int s = 0; s < 2; s++) {
                f32x4 z = {0.f, 0.f, 0.f, 0.f};
                z = MFMA16(kf0, qf[s][0], z);
                z = MFMA16(kf1, qf[s][1], z);
                sacc[s][t] = z;
            }
        }
        __builtin_amdgcn_s_setprio(0);

        // V^T A-fragments (shared by both subtiles), contiguous b128.
        bf16x8 vf[2][4];
#pragma unroll
        for (int dt = 0; dt < 4; dt++) {
            const char* rowv = vb + (16 * dt + lr) * 128;
            vf[0][dt] = *(const bf16x8*)(rowv + ((16 * lg) ^ swz));
            vf[1][dt] = *(const bf16x8*)(rowv + ((64 + 16 * lg) ^ swz));
        }

        // per-subtile: no-shift softmax then PV + psum
#pragma unroll
        for (int s = 0; s < 2; s++) {
            bf16x8 pb[2];
#pragma unroll
            for (int c = 0; c < 2; c++) {
#pragma unroll
                for (int u = 0; u < 2; u++) {
#pragma unroll
                    for (int r = 0; r < 4; r++) {
                        float ev = __builtin_exp2f(sacc[s][2 * c + u][r]);
                        pb[c][4 * u + r] = (bf16)ev;
                    }
                }
            }
            __builtin_amdgcn_s_setprio(1);
#pragma unroll
            for (int dt = 0; dt < 4; dt++) {
                oa[s][dt] = MFMA16(vf[0][dt], pb[0], oa[s][dt]);
                oa[s][dt] = MFMA16(vf[1][dt], pb[1], oa[s][dt]);
            }
            psacc[s] = MFMA16(onesf, pb[0], psacc[s]);
            psacc[s] = MFMA16(onesf, pb[1], psacc[s]);
            __builtin_amdgcn_s_setprio(0);
        }
    };

    constexpr int nt = 64 / NSPLIT;
    const int t0 = zid * nt;

    char* cur = &kv_lds[0][0];
    char* nxt = &kv_lds[1][0];

    stage(t0, cur);
    stage(t0 + 1, nxt);

    for (int t = 0; t < nt; t++) {
        if (t + 1 < nt) asm volatile("s_waitcnt vmcnt(2)" ::: "memory");
        else            asm volatile("s_waitcnt vmcnt(0)" ::: "memory");
        __builtin_amdgcn_s_barrier();       // tile t visible to all waves
        compute(cur);
        asm volatile("" ::: "memory");
        __builtin_amdgcn_s_barrier();       // all waves done reading cur
        if (t + 2 < nt) stage(t0 + t + 2, cur);
        char* tmp = cur; cur = nxt; nxt = tmp;
    }

    // partials: Op[z][row][c] bf16 (unnormalized), ps[z][bh][q]
    const int b = bh >> 2, hd = bh & 3;
#pragma unroll
    for (int s = 0; s < 2; s++) {
        const int q = qw + 16 * s + lr;
        bf16* Oz = Op + (size_t)zid * 8192 * 256
                      + ((size_t)b * NN + q) * CC + hd * 64;
#pragma unroll
        for (int dt = 0; dt < 4; dt++) {
            bf16x4 o4;
#pragma unroll
            for (int i = 0; i < 4; i++) o4[i] = (bf16)oa[s][dt][i];
            *(bf16x4*)&Oz[16 * dt + 4 * lg] = o4;
        }
        ps[((size_t)zid * BH + bh) * NN + q] = psacc[s][0];
    }
}

// ---------------------------------------------------------------------------
// Proj GEMM with fused kv-split combine (bf16 partials):
// A[row][c] = (sum_z Opz) * rinv(row, c>>6), cast bf16,
// then A @ W^T + bias -> out fp32.  BM=128, BN=64. grid (64, 4)
// ---------------------------------------------------------------------------
template<int NSPLIT>
__global__ __launch_bounds__(256) void gemm_proj(const bf16* __restrict__ Op,
                                                 const float* __restrict__ ps,
                                                 const bf16* __restrict__ W,
                                                 const float* __restrict__ bias,
                                                 float* __restrict__ Out) {
    const int wave = threadIdx.x >> 6;
    const int lane = threadIdx.x & 63;
    const int lr = lane & 15;
    const int lg = lane >> 4;
    const int row0 = blockIdx.x * 128 + wave * 32;
    const int col0 = blockIdx.y * 64;

    // rinv per (own row i, head h)
    float rinv[2][4];
#pragma unroll
    for (int i = 0; i < 2; i++) {
        int row = row0 + 16 * i + lr;
        int n = row & 4095, b = row >> 12;
#pragma unroll
        for (int h = 0; h < 4; h++) {
            float s0 = 0.0f;
#pragma unroll
            for (int z = 0; z < NSPLIT; z++)
                s0 += ps[((size_t)z * BH + b * 4 + h) * NN + n];
            rinv[i][h] = 1.0f / s0;
        }
    }

    f32x4 acc[2][4] = {};
    for (int k0 = 0; k0 < 256; k0 += 32) {
        const int h = k0 >> 6;
        bf16x8 a[2], b4[4];
#pragma unroll
        for (int i = 0; i < 2; i++) {
            size_t base = (size_t)(row0 + 16 * i + lr) * 256 + k0 + 8 * lg;
            float av[8] = {};
#pragma unroll
            for (int z = 0; z < NSPLIT; z++) {
                bf16x8 u = *(const bf16x8*)&Op[base + (size_t)z * 8192 * 256];
#pragma unroll
                for (int j = 0; j < 8; j++) av[j] += (float)u[j];
            }
            const float rv = rinv[i][h];
#pragma unroll
            for (int j = 0; j < 8; j++) a[i][j] = (bf16)(av[j] * rv);
        }
#pragma unroll
        for (int t = 0; t < 4; t++)
            b4[t] = *(const bf16x8*)&W[(size_t)(col0 + 16 * t + lr) * 256 + k0 + 8 * lg];
#pragma unroll
        for (int i = 0; i < 2; i++)
#pragma unroll
            for (int t = 0; t < 4; t++)
                acc[i][t] = MFMA16(a[i], b4[t], acc[i][t]);
    }
#pragma unroll
    for (int t = 0; t < 4; t++) {
        float bv = bias[col0 + 16 * t + lr];
#pragma unroll
        for (int i = 0; i < 2; i++) {
#pragma unroll
            for (int r = 0; r < 4; r++) {
                int row = row0 + 16 * i + 4 * lg + r;
                Out[(size_t)row * 256 + col0 + 16 * t + lr] = acc[i][t][r] + bv;
            }
        }
    }
}

// ---------------------------------------------------------------------------
extern "C" void kernel_launch(void* const* d_in, const int* in_sizes, int n_in,
                              void* d_out, int out_size, void* d_ws, size_t ws_size,
                              hipStream_t stream) {
    const float* x      = (const float*)d_in[0];
    const float* w_qkv  = (const float*)d_in[1];
    const float* w_proj = (const float*)d_in[2];
    const float* b_proj = (const float*)d_in[3];
    float* out = (float*)d_out;

    char* ws = (char*)d_ws;
    size_t off = 0;
    auto alloc = [&](size_t bytes) { void* p = ws + off; off += (bytes + 255) & ~(size_t)255; return p; };

    bf16* xb  = (bf16*)alloc((size_t)8192 * 256 * 2);
    bf16* wqb = (bf16*)alloc((size_t)768 * 256 * 2);
    bf16* wpb = (bf16*)alloc((size_t)256 * 256 * 2);
    bf16* Qb  = (bf16*)alloc((size_t)BH * NN * DD * 2);
    bf16* Kb  = (bf16*)alloc((size_t)BH * NN * DD * 2);
    bf16* Vtb = (bf16*)alloc((size_t)BH * NN * DD * 2);

    const size_t opBytes = (size_t)8192 * 256 * 2;   // 4 MiB per split
    const size_t psBytes = (size_t)BH * NN * 4;      // 128 KiB per split
    const size_t perSplit = ((opBytes + 255) & ~(size_t)255) + ((psBytes + 255) & ~(size_t)255);
    const size_t rem = (ws_size > off) ? (ws_size - off) : 0;
    const int nsplit = (rem >= 4 * perSplit) ? 4 : ((rem >= 2 * perSplit) ? 2 : 1);

    bf16*  Op = (bf16*)alloc(opBytes * nsplit);
    float* ps = (float*)alloc(psBytes * nsplit);

    cvt_all<<<2304, 256, 0, stream>>>(x, w_qkv, w_proj, xb, wqb, wpb);
    gemm_qkv<<<dim3(64, 12), 256, 0, stream>>>(xb, wqb, Qb, Kb, Vtb);
    if (nsplit == 4) {
        flash_attn<4><<<dim3(16, 8, 4), 512, 0, stream>>>(Qb, Kb, Vtb, Op, ps);
        gemm_proj<4><<<dim3(64, 4), 256, 0, stream>>>(Op, ps, wpb, b_proj, out);
    } else if (nsplit == 2) {
        flash_attn<2><<<dim3(16, 8, 2), 512, 0, stream>>>(Qb, Kb, Vtb, Op, ps);
        gemm_proj<2><<<dim3(64, 4), 256, 0, stream>>>(Op, ps, wpb, b_proj, out);
    } else {
        flash_attn<1><<<dim3(16, 8, 1), 512, 0, stream>>>(Qb, Kb, Vtb, Op, ps);
        gemm_proj<1><<<dim3(64, 4), 256, 0, stream>>>(Op, ps, wpb, b_proj, out);
    }
}

// Round 3
// 102.785 us; speedup vs baseline: 1.0494x; 1.0494x over previous
//
#include <hip/hip_runtime.h>
#include <hip/hip_bf16.h>
#include <stdint.h>

typedef __bf16 bf16;
typedef __bf16 bf16x8 __attribute__((ext_vector_type(8)));
typedef __bf16 bf16x4 __attribute__((ext_vector_type(4)));
typedef float  f32x4  __attribute__((ext_vector_type(4)));

#define MFMA16(a, b, c) __builtin_amdgcn_mfma_f32_16x16x32_bf16((a), (b), (c), 0, 0, 0)

// Problem constants
#define BB   2
#define NN   4096
#define CC   256
#define HH   4
#define DD   64
#define BH   8          // BB*HH
#define SL2E 0.1803368801111244f   // (1/8) * log2(e), folded into Q

__device__ __forceinline__ void gload_lds16(const void* g, void* l) {
    __builtin_amdgcn_global_load_lds(
        (const __attribute__((address_space(1))) void*)g,
        (__attribute__((address_space(3))) void*)l, 16, 0, 0);
}

// ---------------------------------------------------------------------------
// fp32 -> bf16 convert, all three inputs in one launch.
// segment sizes (in float4): x 524288 | w_qkv 49152 | w_proj 16384
// ---------------------------------------------------------------------------
__global__ __launch_bounds__(256) void cvt_all(const float* __restrict__ x,
                                               const float* __restrict__ wq,
                                               const float* __restrict__ wp,
                                               bf16* __restrict__ xb,
                                               bf16* __restrict__ wqb,
                                               bf16* __restrict__ wpb) {
    int i = blockIdx.x * 256 + threadIdx.x;
    const float* src; bf16* dst; int j;
    if (i < 524288)      { src = x;  dst = xb;  j = i; }
    else if (i < 573440) { src = wq; dst = wqb; j = i - 524288; }
    else if (i < 589824) { src = wp; dst = wpb; j = i - 573440; }
    else return;
    f32x4 v = ((const f32x4*)src)[j];
    bf16x4 o;
    o[0] = (bf16)v[0]; o[1] = (bf16)v[1]; o[2] = (bf16)v[2]; o[3] = (bf16)v[3];
    ((bf16x4*)dst)[j] = o;
}

// ---------------------------------------------------------------------------
// QKV GEMM: X[8192][256] @ W[768][256]^T.
// Q written scaled by SL2E (so attention exp input is exp2-domain directly).
// V written transposed AND column-permuted as Vt [BH][D][N']:
// logical column kv = 32g+16u+4w+r stored at n' = 32g+8w+4u+r, so the
// flash PV A-fragment (psi-permuted k) is a contiguous 16B read.
// BM=128 (4 waves x 32 rows), BN=64. grid (64,12)
// ---------------------------------------------------------------------------
__global__ __launch_bounds__(256) void gemm_qkv(const bf16* __restrict__ X,
                                                const bf16* __restrict__ W,
                                                bf16* __restrict__ Q,
                                                bf16* __restrict__ K,
                                                bf16* __restrict__ Vt) {
    const int wave = threadIdx.x >> 6;
    const int lane = threadIdx.x & 63;
    const int lr = lane & 15;
    const int lg = lane >> 4;
    const int row0 = blockIdx.x * 128 + wave * 32;
    const int col0 = blockIdx.y * 64;

    f32x4 acc[2][4] = {};
    for (int k0 = 0; k0 < 256; k0 += 32) {
        bf16x8 a[2], b[4];
#pragma unroll
        for (int i = 0; i < 2; i++)
            a[i] = *(const bf16x8*)&X[(size_t)(row0 + 16 * i + lr) * 256 + k0 + 8 * lg];
#pragma unroll
        for (int t = 0; t < 4; t++)
            b[t] = *(const bf16x8*)&W[(size_t)(col0 + 16 * t + lr) * 256 + k0 + 8 * lg];
#pragma unroll
        for (int i = 0; i < 2; i++)
#pragma unroll
            for (int t = 0; t < 4; t++)
                acc[i][t] = MFMA16(a[i], b[t], acc[i][t]);
    }

    const int s = col0 >> 8;          // 0=Q 1=K 2=V
    const int h = (col0 >> 6) & 3;
    if (s == 2) {
#pragma unroll
        for (int i = 0; i < 2; i++) {
#pragma unroll
            for (int t = 0; t < 4; t++) {
                int row = row0 + 16 * i + 4 * lg;     // n base (4 consecutive)
                int d   = 16 * t + lr;
                int bh  = ((row >> 12) << 2) | h;
                int nb  = row & 4095;
                int g   = nb >> 5, m = (nb >> 2) & 7;
                int np  = (g << 5) + ((m & 3) << 3) + ((m >> 2) << 2);
                bf16x4 o4;
#pragma unroll
                for (int r = 0; r < 4; r++) o4[r] = (bf16)acc[i][t][r];
                *(bf16x4*)&Vt[((size_t)bh * DD + d) * NN + np] = o4;
            }
        }
    } else {
        bf16* dst = (s == 0) ? Q : K;
        const float sc = (s == 0) ? SL2E : 1.0f;
#pragma unroll
        for (int i = 0; i < 2; i++) {
#pragma unroll
            for (int t = 0; t < 4; t++) {
#pragma unroll
                for (int r = 0; r < 4; r++) {
                    int row = row0 + 16 * i + 4 * lg + r;
                    int d   = 16 * t + lr;
                    int bh  = ((row >> 12) << 2) | h;
                    int n   = row & 4095;
                    dst[((size_t)bh * NN + n) * DD + d] = (bf16)(acc[i][t][r] * sc);
                }
            }
        }
    }
}

// ---------------------------------------------------------------------------
// Flash attention: swapped 16x16 QK^T, TWO q-subtiles per wave (K/V LDS
// fragments shared -> LDS read traffic halved), in-register no-shift
// softmax, permuted-k PV with b128 V-fragments, psum via ones-MFMA,
// 2-buffer staging (counted vmcnt), kv-split across NSPLIT (template).
// 8 waves/block (512 thr, 256 q-rows): grid 512 blocks = 2 resident
// blocks/CU = 16 waves/CU.  launch_bounds(512,2) — do NOT clamp regs to
// 128/wave: that spilled (r2: WRITE 47MB, VALUBusy 43%, -10%% perf).
// XCD-aware bijective block swizzle for KV L2 locality.
// Partials: Op [z][8192][256] bf16 (AO layout, unnormalized), ps [z][BH][N] f32.
// grid (N/256, BH, NSPLIT), 512 threads (8 waves x 32 q-rows).
// ---------------------------------------------------------------------------
template<int NSPLIT>
__global__ __launch_bounds__(512, 2) void flash_attn(const bf16* __restrict__ Q,
                                                     const bf16* __restrict__ K,
                                                     const bf16* __restrict__ Vt,
                                                     bf16* __restrict__ Op,
                                                     float* __restrict__ ps) {
    __shared__ __align__(16) char kv_lds[2][16384];

    // bijective XCD swizzle: total = 128*NSPLIT blocks, chunk = total/8
    const int id  = blockIdx.x + 16 * (blockIdx.y + 8 * blockIdx.z);
    constexpr int CHUNK = 16 * NSPLIT;
    const int nid = (id & 7) * CHUNK + (id >> 3);
    const int qx  = nid & 15;            // q-block index
    const int g   = nid >> 4;
    const int bh  = g & 7;               // head index
    const int zid = g >> 3;              // kv-split index

    const int wave = threadIdx.x >> 6;
    const int lane = threadIdx.x & 63;
    const int lr   = lane & 15;
    const int lg   = lane >> 4;
    const int tid  = threadIdx.x;
    const int swz  = (lr & 7) << 4;

    const char* Khb  = (const char*)(K  + (size_t)bh * NN * DD);   // row stride 128B
    const char* Vthb = (const char*)(Vt + (size_t)bh * DD * NN);   // row stride 8192B
    const bf16* Qh   = Q + (size_t)bh * NN * DD;

    const int qw = qx * 256 + wave * 32;

    // Q B-fragments (pre-scaled by SL2E), 2 subtiles: q = qw + 16s + lr
    bf16x8 qf[2][2];
#pragma unroll
    for (int s = 0; s < 2; s++) {
        qf[s][0] = *(const bf16x8*)&Qh[(size_t)(qw + 16 * s + lr) * DD + 8 * lg];
        qf[s][1] = *(const bf16x8*)&Qh[(size_t)(qw + 16 * s + lr) * DD + 32 + 8 * lg];
    }

    const int L  = tid * 16;                       // 0..8176
    const int r0 = L >> 7;                         // 0..63
    const int c0 = (L & 127) ^ ((r0 & 7) << 4);    // inverse-swizzled source col

    bf16x8 onesf;
#pragma unroll
    for (int j = 0; j < 8; j++) onesf[j] = (bf16)1.0f;

    f32x4 oa[2][4] = {};     // [subtile][dt]: O[q][d=16dt+4lg+r] unnormalized
    f32x4 psacc[2] = {};     // per-subtile ones-MFMA psum

    auto stage = [&](int t, char* buf) {
        const int kv0 = t * 64;
        gload_lds16(Khb + (size_t)(kv0 + r0) * 128 + c0,     buf + L);
        gload_lds16(Vthb + (size_t)r0 * 8192 + kv0 * 2 + c0, buf + 8192 + L);
    };

    auto compute = [&](const char* buf) {
        const char* kb = buf;
        const char* vb = buf + 8192;

        // S^T = K . Q^T for both q-subtiles; K fragments read ONCE.
        f32x4 sacc[2][4];
        __builtin_amdgcn_s_setprio(1);
#pragma unroll
        for (int t = 0; t < 4; t++) {
            const char* rowk = kb + (16 * t + lr) * 128;
            bf16x8 kf0 = *(const bf16x8*)(rowk + ((16 * lg) ^ swz));
            bf16x8 kf1 = *(const bf16x8*)(rowk + ((64 + 16 * lg) ^ swz));
#pragma unroll
            for (int s = 0; s < 2; s++) {
                f32x4 z = {0.f, 0.f, 0.f, 0.f};
                z = MFMA16(kf0, qf[s][0], z);
                z = MFMA16(kf1, qf[s][1], z);
                sacc[s][t] = z;
            }
        }
        __builtin_amdgcn_s_setprio(0);

        // V^T A-fragments (shared by both subtiles), contiguous b128.
        bf16x8 vf[2][4];
#pragma unroll
        for (int dt = 0; dt < 4; dt++) {
            const char* rowv = vb + (16 * dt + lr) * 128;
            vf[0][dt] = *(const bf16x8*)(rowv + ((16 * lg) ^ swz));
            vf[1][dt] = *(const bf16x8*)(rowv + ((64 + 16 * lg) ^ swz));
        }

        // per-subtile: no-shift softmax then PV + psum
#pragma unroll
        for (int s = 0; s < 2; s++) {
            bf16x8 pb[2];
#pragma unroll
            for (int c = 0; c < 2; c++) {
#pragma unroll
                for (int u = 0; u < 2; u++) {
#pragma unroll
                    for (int r = 0; r < 4; r++) {
                        float ev = __builtin_exp2f(sacc[s][2 * c + u][r]);
                        pb[c][4 * u + r] = (bf16)ev;
                    }
                }
            }
            __builtin_amdgcn_s_setprio(1);
#pragma unroll
            for (int dt = 0; dt < 4; dt++) {
                oa[s][dt] = MFMA16(vf[0][dt], pb[0], oa[s][dt]);
                oa[s][dt] = MFMA16(vf[1][dt], pb[1], oa[s][dt]);
            }
            psacc[s] = MFMA16(onesf, pb[0], psacc[s]);
            psacc[s] = MFMA16(onesf, pb[1], psacc[s]);
            __builtin_amdgcn_s_setprio(0);
        }
    };

    constexpr int nt = 64 / NSPLIT;
    const int t0 = zid * nt;

    char* cur = &kv_lds[0][0];
    char* nxt = &kv_lds[1][0];

    stage(t0, cur);
    stage(t0 + 1, nxt);

    for (int t = 0; t < nt; t++) {
        if (t + 1 < nt) asm volatile("s_waitcnt vmcnt(2)" ::: "memory");
        else            asm volatile("s_waitcnt vmcnt(0)" ::: "memory");
        __builtin_amdgcn_s_barrier();       // tile t visible to all waves
        compute(cur);
        asm volatile("" ::: "memory");
        __builtin_amdgcn_s_barrier();       // all waves done reading cur
        if (t + 2 < nt) stage(t0 + t + 2, cur);
        char* tmp = cur; cur = nxt; nxt = tmp;
    }

    // partials: Op[z][row][c] bf16 (unnormalized), ps[z][bh][q]
    const int b = bh >> 2, hd = bh & 3;
#pragma unroll
    for (int s = 0; s < 2; s++) {
        const int q = qw + 16 * s + lr;
        bf16* Oz = Op + (size_t)zid * 8192 * 256
                      + ((size_t)b * NN + q) * CC + hd * 64;
#pragma unroll
        for (int dt = 0; dt < 4; dt++) {
            bf16x4 o4;
#pragma unroll
            for (int i = 0; i < 4; i++) o4[i] = (bf16)oa[s][dt][i];
            *(bf16x4*)&Oz[16 * dt + 4 * lg] = o4;
        }
        ps[((size_t)zid * BH + bh) * NN + q] = psacc[s][0];
    }
}

// ---------------------------------------------------------------------------
// Proj GEMM with fused kv-split combine (bf16 partials):
// A[row][c] = (sum_z Opz) * rinv(row, c>>6), cast bf16,
// then A @ W^T + bias -> out fp32.  BM=128, BN=64. grid (64, 4)
// ---------------------------------------------------------------------------
template<int NSPLIT>
__global__ __launch_bounds__(256) void gemm_proj(const bf16* __restrict__ Op,
                                                 const float* __restrict__ ps,
                                                 const bf16* __restrict__ W,
                                                 const float* __restrict__ bias,
                                                 float* __restrict__ Out) {
    const int wave = threadIdx.x >> 6;
    const int lane = threadIdx.x & 63;
    const int lr = lane & 15;
    const int lg = lane >> 4;
    const int row0 = blockIdx.x * 128 + wave * 32;
    const int col0 = blockIdx.y * 64;

    // rinv per (own row i, head h)
    float rinv[2][4];
#pragma unroll
    for (int i = 0; i < 2; i++) {
        int row = row0 + 16 * i + lr;
        int n = row & 4095, b = row >> 12;
#pragma unroll
        for (int h = 0; h < 4; h++) {
            float s0 = 0.0f;
#pragma unroll
            for (int z = 0; z < NSPLIT; z++)
                s0 += ps[((size_t)z * BH + b * 4 + h) * NN + n];
            rinv[i][h] = 1.0f / s0;
        }
    }

    f32x4 acc[2][4] = {};
    for (int k0 = 0; k0 < 256; k0 += 32) {
        const int h = k0 >> 6;
        bf16x8 a[2], b4[4];
#pragma unroll
        for (int i = 0; i < 2; i++) {
            size_t base = (size_t)(row0 + 16 * i + lr) * 256 + k0 + 8 * lg;
            float av[8] = {};
#pragma unroll
            for (int z = 0; z < NSPLIT; z++) {
                bf16x8 u = *(const bf16x8*)&Op[base + (size_t)z * 8192 * 256];
#pragma unroll
                for (int j = 0; j < 8; j++) av[j] += (float)u[j];
            }
            const float rv = rinv[i][h];
#pragma unroll
            for (int j = 0; j < 8; j++) a[i][j] = (bf16)(av[j] * rv);
        }
#pragma unroll
        for (int t = 0; t < 4; t++)
            b4[t] = *(const bf16x8*)&W[(size_t)(col0 + 16 * t + lr) * 256 + k0 + 8 * lg];
#pragma unroll
        for (int i = 0; i < 2; i++)
#pragma unroll
            for (int t = 0; t < 4; t++)
                acc[i][t] = MFMA16(a[i], b4[t], acc[i][t]);
    }
#pragma unroll
    for (int t = 0; t < 4; t++) {
        float bv = bias[col0 + 16 * t + lr];
#pragma unroll
        for (int i = 0; i < 2; i++) {
#pragma unroll
            for (int r = 0; r < 4; r++) {
                int row = row0 + 16 * i + 4 * lg + r;
                Out[(size_t)row * 256 + col0 + 16 * t + lr] = acc[i][t][r] + bv;
            }
        }
    }
}

// ---------------------------------------------------------------------------
extern "C" void kernel_launch(void* const* d_in, const int* in_sizes, int n_in,
                              void* d_out, int out_size, void* d_ws, size_t ws_size,
                              hipStream_t stream) {
    const float* x      = (const float*)d_in[0];
    const float* w_qkv  = (const float*)d_in[1];
    const float* w_proj = (const float*)d_in[2];
    const float* b_proj = (const float*)d_in[3];
    float* out = (float*)d_out;

    char* ws = (char*)d_ws;
    size_t off = 0;
    auto alloc = [&](size_t bytes) { void* p = ws + off; off += (bytes + 255) & ~(size_t)255; return p; };

    bf16* xb  = (bf16*)alloc((size_t)8192 * 256 * 2);
    bf16* wqb = (bf16*)alloc((size_t)768 * 256 * 2);
    bf16* wpb = (bf16*)alloc((size_t)256 * 256 * 2);
    bf16* Qb  = (bf16*)alloc((size_t)BH * NN * DD * 2);
    bf16* Kb  = (bf16*)alloc((size_t)BH * NN * DD * 2);
    bf16* Vtb = (bf16*)alloc((size_t)BH * NN * DD * 2);

    const size_t opBytes = (size_t)8192 * 256 * 2;   // 4 MiB per split
    const size_t psBytes = (size_t)BH * NN * 4;      // 128 KiB per split
    const size_t perSplit = ((opBytes + 255) & ~(size_t)255) + ((psBytes + 255) & ~(size_t)255);
    const size_t rem = (ws_size > off) ? (ws_size - off) : 0;
    const int nsplit = (rem >= 4 * perSplit) ? 4 : ((rem >= 2 * perSplit) ? 2 : 1);

    bf16*  Op = (bf16*)alloc(opBytes * nsplit);
    float* ps = (float*)alloc(psBytes * nsplit);

    cvt_all<<<2304, 256, 0, stream>>>(x, w_qkv, w_proj, xb, wqb, wpb);
    gemm_qkv<<<dim3(64, 12), 256, 0, stream>>>(xb, wqb, Qb, Kb, Vtb);
    if (nsplit == 4) {
        flash_attn<4><<<dim3(16, 8, 4), 512, 0, stream>>>(Qb, Kb, Vtb, Op, ps);
        gemm_proj<4><<<dim3(64, 4), 256, 0, stream>>>(Op, ps, wpb, b_proj, out);
    } else if (nsplit == 2) {
        flash_attn<2><<<dim3(16, 8, 2), 512, 0, stream>>>(Qb, Kb, Vtb, Op, ps);
        gemm_proj<2><<<dim3(64, 4), 256, 0, stream>>>(Op, ps, wpb, b_proj, out);
    } else {
        flash_attn<1><<<dim3(16, 8, 1), 512, 0, stream>>>(Qb, Kb, Vtb, Op, ps);
        gemm_proj<1><<<dim3(64, 4), 256, 0, stream>>>(Op, ps, wpb, b_proj, out);
    }
}

// Round 4
// 101.019 us; speedup vs baseline: 1.0677x; 1.0175x over previous
//
#include <hip/hip_runtime.h>
#include <hip/hip_bf16.h>
#include <stdint.h>

typedef __bf16 bf16;
typedef __bf16 bf16x8 __attribute__((ext_vector_type(8)));
typedef __bf16 bf16x4 __attribute__((ext_vector_type(4)));
typedef float  f32x4  __attribute__((ext_vector_type(4)));

#define MFMA16(a, b, c) __builtin_amdgcn_mfma_f32_16x16x32_bf16((a), (b), (c), 0, 0, 0)

// Problem constants
#define BB   2
#define NN   4096
#define CC   256
#define HH   4
#define DD   64
#define BH   8          // BB*HH
#define SL2E 0.1803368801111244f   // (1/8) * log2(e), folded into Q

__device__ __forceinline__ void gload_lds16(const void* g, void* l) {
    __builtin_amdgcn_global_load_lds(
        (const __attribute__((address_space(1))) void*)g,
        (__attribute__((address_space(3))) void*)l, 16, 0, 0);
}

// ---------------------------------------------------------------------------
// fp32 -> bf16 convert, all three inputs in one launch.
// segment sizes (in float4): x 524288 | w_qkv 49152 | w_proj 16384
// ---------------------------------------------------------------------------
__global__ __launch_bounds__(256) void cvt_all(const float* __restrict__ x,
                                               const float* __restrict__ wq,
                                               const float* __restrict__ wp,
                                               bf16* __restrict__ xb,
                                               bf16* __restrict__ wqb,
                                               bf16* __restrict__ wpb) {
    int i = blockIdx.x * 256 + threadIdx.x;
    const float* src; bf16* dst; int j;
    if (i < 524288)      { src = x;  dst = xb;  j = i; }
    else if (i < 573440) { src = wq; dst = wqb; j = i - 524288; }
    else if (i < 589824) { src = wp; dst = wpb; j = i - 573440; }
    else return;
    f32x4 v = ((const f32x4*)src)[j];
    bf16x4 o;
    o[0] = (bf16)v[0]; o[1] = (bf16)v[1]; o[2] = (bf16)v[2]; o[3] = (bf16)v[3];
    ((bf16x4*)dst)[j] = o;
}

// ---------------------------------------------------------------------------
// QKV GEMM: X[8192][256] @ W[768][256]^T.
// Q written scaled by SL2E (so attention exp input is exp2-domain directly).
// V written transposed AND column-permuted as Vt [BH][D][N']:
// logical column kv = 32g+16u+4w+r stored at n' = 32g+8w+4u+r, so the
// flash PV A-fragment (psi-permuted k) is a contiguous 16B read.
// BM=128 (4 waves x 32 rows), BN=64. grid (64,12)
// ---------------------------------------------------------------------------
__global__ __launch_bounds__(256) void gemm_qkv(const bf16* __restrict__ X,
                                                const bf16* __restrict__ W,
                                                bf16* __restrict__ Q,
                                                bf16* __restrict__ K,
                                                bf16* __restrict__ Vt) {
    const int wave = threadIdx.x >> 6;
    const int lane = threadIdx.x & 63;
    const int lr = lane & 15;
    const int lg = lane >> 4;
    const int row0 = blockIdx.x * 128 + wave * 32;
    const int col0 = blockIdx.y * 64;

    f32x4 acc[2][4] = {};
    for (int k0 = 0; k0 < 256; k0 += 32) {
        bf16x8 a[2], b[4];
#pragma unroll
        for (int i = 0; i < 2; i++)
            a[i] = *(const bf16x8*)&X[(size_t)(row0 + 16 * i + lr) * 256 + k0 + 8 * lg];
#pragma unroll
        for (int t = 0; t < 4; t++)
            b[t] = *(const bf16x8*)&W[(size_t)(col0 + 16 * t + lr) * 256 + k0 + 8 * lg];
#pragma unroll
        for (int i = 0; i < 2; i++)
#pragma unroll
            for (int t = 0; t < 4; t++)
                acc[i][t] = MFMA16(a[i], b[t], acc[i][t]);
    }

    const int s = col0 >> 8;          // 0=Q 1=K 2=V
    const int h = (col0 >> 6) & 3;
    if (s == 2) {
#pragma unroll
        for (int i = 0; i < 2; i++) {
#pragma unroll
            for (int t = 0; t < 4; t++) {
                int row = row0 + 16 * i + 4 * lg;     // n base (4 consecutive)
                int d   = 16 * t + lr;
                int bh  = ((row >> 12) << 2) | h;
                int nb  = row & 4095;
                int g   = nb >> 5, m = (nb >> 2) & 7;
                int np  = (g << 5) + ((m & 3) << 3) + ((m >> 2) << 2);
                bf16x4 o4;
#pragma unroll
                for (int r = 0; r < 4; r++) o4[r] = (bf16)acc[i][t][r];
                *(bf16x4*)&Vt[((size_t)bh * DD + d) * NN + np] = o4;
            }
        }
    } else {
        bf16* dst = (s == 0) ? Q : K;
        const float sc = (s == 0) ? SL2E : 1.0f;
#pragma unroll
        for (int i = 0; i < 2; i++) {
#pragma unroll
            for (int t = 0; t < 4; t++) {
#pragma unroll
                for (int r = 0; r < 4; r++) {
                    int row = row0 + 16 * i + 4 * lg + r;
                    int d   = 16 * t + lr;
                    int bh  = ((row >> 12) << 2) | h;
                    int n   = row & 4095;
                    dst[((size_t)bh * NN + n) * DD + d] = (bf16)(acc[i][t][r] * sc);
                }
            }
        }
    }
}

// ---------------------------------------------------------------------------
// Flash attention: swapped 16x16 QK^T, FOUR q-subtiles per wave (64 q-rows/
// wave) so the shared K/V LDS fragments amortize over 2x more MFMA work
// (r0-r3 showed dur invariant to occupancy: the limiter is per-block
// critical path, dominated by 8x-duplicated LDS fragment reads + exp VALU).
// exp2 fused into the QK t-loop: sacc[s][t] is final within its t-iteration
// (D-reduction completes inside), so S never materializes as a 64-reg array
// -> P goes straight to bf16 pb[4][2]. In-register no-shift softmax,
// permuted-k PV with b128 V-fragments, psum via ones-MFMA, 2-buffer staging
// (counted vmcnt), kv-split across NSPLIT. XCD-aware bijective swizzle.
// Partials: Op [z][8192][256] bf16 (AO layout, unnormalized), ps [z][BH][N].
// grid (N/256, BH, NSPLIT), 256 threads (4 waves x 64 q-rows).
// ---------------------------------------------------------------------------
template<int NSPLIT>
__global__ __launch_bounds__(256, 2) void flash_attn(const bf16* __restrict__ Q,
                                                     const bf16* __restrict__ K,
                                                     const bf16* __restrict__ Vt,
                                                     bf16* __restrict__ Op,
                                                     float* __restrict__ ps) {
    __shared__ __align__(16) char kv_lds[2][16384];

    // bijective XCD swizzle: total = 128*NSPLIT blocks, chunk = total/8
    const int id  = blockIdx.x + 16 * (blockIdx.y + 8 * blockIdx.z);
    constexpr int CHUNK = 16 * NSPLIT;
    const int nid = (id & 7) * CHUNK + (id >> 3);
    const int qx  = nid & 15;            // q-block index
    const int g   = nid >> 4;
    const int bh  = g & 7;               // head index
    const int zid = g >> 3;              // kv-split index

    const int wave = threadIdx.x >> 6;
    const int lane = threadIdx.x & 63;
    const int lr   = lane & 15;
    const int lg   = lane >> 4;
    const int tid  = threadIdx.x;
    const int swz  = (lr & 7) << 4;

    const char* Khb  = (const char*)(K  + (size_t)bh * NN * DD);   // row stride 128B
    const char* Vthb = (const char*)(Vt + (size_t)bh * DD * NN);   // row stride 8192B
    const bf16* Qh   = Q + (size_t)bh * NN * DD;

    const int qw = qx * 256 + wave * 64;

    // Q B-fragments (pre-scaled by SL2E), 4 subtiles: q = qw + 16s + lr
    bf16x8 qf[4][2];
#pragma unroll
    for (int s = 0; s < 4; s++) {
        qf[s][0] = *(const bf16x8*)&Qh[(size_t)(qw + 16 * s + lr) * DD + 8 * lg];
        qf[s][1] = *(const bf16x8*)&Qh[(size_t)(qw + 16 * s + lr) * DD + 32 + 8 * lg];
    }

    const int L  = tid * 16;                       // 0..4080
    const int r0 = L >> 7;                         // 0..31
    const int c0 = (L & 127) ^ ((r0 & 7) << 4);    // inverse-swizzled source col

    bf16x8 onesf;
#pragma unroll
    for (int j = 0; j < 8; j++) onesf[j] = (bf16)1.0f;

    f32x4 oa[4][4] = {};     // [subtile][dt]: O[q][d=16dt+4lg+r] unnormalized
    f32x4 psacc[4] = {};     // per-subtile ones-MFMA psum

    auto stage = [&](int t, char* buf) {
        const int kv0 = t * 64;
        gload_lds16(Khb + (size_t)(kv0 + r0) * 128 + c0,             buf + L);
        gload_lds16(Khb + (size_t)(kv0 + r0 + 32) * 128 + c0,        buf + 4096 + L);
        gload_lds16(Vthb + (size_t)r0 * 8192 + kv0 * 2 + c0,         buf + 8192 + L);
        gload_lds16(Vthb + (size_t)(r0 + 32) * 8192 + kv0 * 2 + c0,  buf + 12288 + L);
    };

    auto compute = [&](const char* buf) {
        const char* kb = buf;
        const char* vb = buf + 8192;

        // S^T = K . Q^T, exp fused per (t,s): sacc is final within its
        // t-iteration, so convert to bf16 P immediately (no S array).
        bf16x8 pb[4][2];
        __builtin_amdgcn_s_setprio(1);
#pragma unroll
        for (int t = 0; t < 4; t++) {
            const char* rowk = kb + (16 * t + lr) * 128;
            bf16x8 kf0 = *(const bf16x8*)(rowk + ((16 * lg) ^ swz));
            bf16x8 kf1 = *(const bf16x8*)(rowk + ((64 + 16 * lg) ^ swz));
#pragma unroll
            for (int s = 0; s < 4; s++) {
                f32x4 z = {0.f, 0.f, 0.f, 0.f};
                z = MFMA16(kf0, qf[s][0], z);
                z = MFMA16(kf1, qf[s][1], z);
#pragma unroll
                for (int r = 0; r < 4; r++)
                    pb[s][t >> 1][4 * (t & 1) + r] = (bf16)__builtin_exp2f(z[r]);
            }
        }
        __builtin_amdgcn_s_setprio(0);

        // V^T A-fragments (shared by all 4 subtiles), contiguous b128.
        bf16x8 vf[2][4];
#pragma unroll
        for (int dt = 0; dt < 4; dt++) {
            const char* rowv = vb + (16 * dt + lr) * 128;
            vf[0][dt] = *(const bf16x8*)(rowv + ((16 * lg) ^ swz));
            vf[1][dt] = *(const bf16x8*)(rowv + ((64 + 16 * lg) ^ swz));
        }

        // PV + psum per subtile
        __builtin_amdgcn_s_setprio(1);
#pragma unroll
        for (int s = 0; s < 4; s++) {
#pragma unroll
            for (int dt = 0; dt < 4; dt++) {
                oa[s][dt] = MFMA16(vf[0][dt], pb[s][0], oa[s][dt]);
                oa[s][dt] = MFMA16(vf[1][dt], pb[s][1], oa[s][dt]);
            }
            psacc[s] = MFMA16(onesf, pb[s][0], psacc[s]);
            psacc[s] = MFMA16(onesf, pb[s][1], psacc[s]);
        }
        __builtin_amdgcn_s_setprio(0);
    };

    constexpr int nt = 64 / NSPLIT;
    const int t0 = zid * nt;

    char* cur = &kv_lds[0][0];
    char* nxt = &kv_lds[1][0];

    stage(t0, cur);
    stage(t0 + 1, nxt);

    for (int t = 0; t < nt; t++) {
        if (t + 1 < nt) asm volatile("s_waitcnt vmcnt(4)" ::: "memory");
        else            asm volatile("s_waitcnt vmcnt(0)" ::: "memory");
        __builtin_amdgcn_s_barrier();       // tile t visible to all waves
        compute(cur);
        asm volatile("" ::: "memory");
        __builtin_amdgcn_s_barrier();       // all waves done reading cur
        if (t + 2 < nt) stage(t0 + t + 2, cur);
        char* tmp = cur; cur = nxt; nxt = tmp;
    }

    // partials: Op[z][row][c] bf16 (unnormalized), ps[z][bh][q]
    const int b = bh >> 2, hd = bh & 3;
#pragma unroll
    for (int s = 0; s < 4; s++) {
        const int q = qw + 16 * s + lr;
        bf16* Oz = Op + (size_t)zid * 8192 * 256
                      + ((size_t)b * NN + q) * CC + hd * 64;
#pragma unroll
        for (int dt = 0; dt < 4; dt++) {
            bf16x4 o4;
#pragma unroll
            for (int i = 0; i < 4; i++) o4[i] = (bf16)oa[s][dt][i];
            *(bf16x4*)&Oz[16 * dt + 4 * lg] = o4;
        }
        ps[((size_t)zid * BH + bh) * NN + q] = psacc[s][0];
    }
}

// ---------------------------------------------------------------------------
// Proj GEMM with fused kv-split combine (bf16 partials):
// A[row][c] = (sum_z Opz) * rinv(row, c>>6), cast bf16,
// then A @ W^T + bias -> out fp32.  BM=128, BN=64. grid (64, 4)
// ---------------------------------------------------------------------------
template<int NSPLIT>
__global__ __launch_bounds__(256) void gemm_proj(const bf16* __restrict__ Op,
                                                 const float* __restrict__ ps,
                                                 const bf16* __restrict__ W,
                                                 const float* __restrict__ bias,
                                                 float* __restrict__ Out) {
    const int wave = threadIdx.x >> 6;
    const int lane = threadIdx.x & 63;
    const int lr = lane & 15;
    const int lg = lane >> 4;
    const int row0 = blockIdx.x * 128 + wave * 32;
    const int col0 = blockIdx.y * 64;

    // rinv per (own row i, head h)
    float rinv[2][4];
#pragma unroll
    for (int i = 0; i < 2; i++) {
        int row = row0 + 16 * i + lr;
        int n = row & 4095, b = row >> 12;
#pragma unroll
        for (int h = 0; h < 4; h++) {
            float s0 = 0.0f;
#pragma unroll
            for (int z = 0; z < NSPLIT; z++)
                s0 += ps[((size_t)z * BH + b * 4 + h) * NN + n];
            rinv[i][h] = 1.0f / s0;
        }
    }

    f32x4 acc[2][4] = {};
    for (int k0 = 0; k0 < 256; k0 += 32) {
        const int h = k0 >> 6;
        bf16x8 a[2], b4[4];
#pragma unroll
        for (int i = 0; i < 2; i++) {
            size_t base = (size_t)(row0 + 16 * i + lr) * 256 + k0 + 8 * lg;
            float av[8] = {};
#pragma unroll
            for (int z = 0; z < NSPLIT; z++) {
                bf16x8 u = *(const bf16x8*)&Op[base + (size_t)z * 8192 * 256];
#pragma unroll
                for (int j = 0; j < 8; j++) av[j] += (float)u[j];
            }
            const float rv = rinv[i][h];
#pragma unroll
            for (int j = 0; j < 8; j++) a[i][j] = (bf16)(av[j] * rv);
        }
#pragma unroll
        for (int t = 0; t < 4; t++)
            b4[t] = *(const bf16x8*)&W[(size_t)(col0 + 16 * t + lr) * 256 + k0 + 8 * lg];
#pragma unroll
        for (int i = 0; i < 2; i++)
#pragma unroll
            for (int t = 0; t < 4; t++)
                acc[i][t] = MFMA16(a[i], b4[t], acc[i][t]);
    }
#pragma unroll
    for (int t = 0; t < 4; t++) {
        float bv = bias[col0 + 16 * t + lr];
#pragma unroll
        for (int i = 0; i < 2; i++) {
#pragma unroll
            for (int r = 0; r < 4; r++) {
                int row = row0 + 16 * i + 4 * lg + r;
                Out[(size_t)row * 256 + col0 + 16 * t + lr] = acc[i][t][r] + bv;
            }
        }
    }
}

// ---------------------------------------------------------------------------
extern "C" void kernel_launch(void* const* d_in, const int* in_sizes, int n_in,
                              void* d_out, int out_size, void* d_ws, size_t ws_size,
                              hipStream_t stream) {
    const float* x      = (const float*)d_in[0];
    const float* w_qkv  = (const float*)d_in[1];
    const float* w_proj = (const float*)d_in[2];
    const float* b_proj = (const float*)d_in[3];
    float* out = (float*)d_out;

    char* ws = (char*)d_ws;
    size_t off = 0;
    auto alloc = [&](size_t bytes) { void* p = ws + off; off += (bytes + 255) & ~(size_t)255; return p; };

    bf16* xb  = (bf16*)alloc((size_t)8192 * 256 * 2);
    bf16* wqb = (bf16*)alloc((size_t)768 * 256 * 2);
    bf16* wpb = (bf16*)alloc((size_t)256 * 256 * 2);
    bf16* Qb  = (bf16*)alloc((size_t)BH * NN * DD * 2);
    bf16* Kb  = (bf16*)alloc((size_t)BH * NN * DD * 2);
    bf16* Vtb = (bf16*)alloc((size_t)BH * NN * DD * 2);

    const size_t opBytes = (size_t)8192 * 256 * 2;   // 4 MiB per split
    const size_t psBytes = (size_t)BH * NN * 4;      // 128 KiB per split
    const size_t perSplit = ((opBytes + 255) & ~(size_t)255) + ((psBytes + 255) & ~(size_t)255);
    const size_t rem = (ws_size > off) ? (ws_size - off) : 0;
    const int nsplit = (rem >= 4 * perSplit) ? 4 : ((rem >= 2 * perSplit) ? 2 : 1);

    bf16*  Op = (bf16*)alloc(opBytes * nsplit);
    float* ps = (float*)alloc(psBytes * nsplit);

    cvt_all<<<2304, 256, 0, stream>>>(x, w_qkv, w_proj, xb, wqb, wpb);
    gemm_qkv<<<dim3(64, 12), 256, 0, stream>>>(xb, wqb, Qb, Kb, Vtb);
    if (nsplit == 4) {
        flash_attn<4><<<dim3(16, 8, 4), 256, 0, stream>>>(Qb, Kb, Vtb, Op, ps);
        gemm_proj<4><<<dim3(64, 4), 256, 0, stream>>>(Op, ps, wpb, b_proj, out);
    } else if (nsplit == 2) {
        flash_attn<2><<<dim3(16, 8, 2), 256, 0, stream>>>(Qb, Kb, Vtb, Op, ps);
        gemm_proj<2><<<dim3(64, 4), 256, 0, stream>>>(Op, ps, wpb, b_proj, out);
    } else {
        flash_attn<1><<<dim3(16, 8, 1), 256, 0, stream>>>(Qb, Kb, Vtb, Op, ps);
        gemm_proj<1><<<dim3(64, 4), 256, 0, stream>>>(Op, ps, wpb, b_proj, out);
    }
}